// Round 2
// baseline (2119.212 us; speedup 1.0000x reference)
//
#include <hip/hip_runtime.h>
#include <hip/hip_bf16.h>

#define NB 16        // expert blocks
#define TOPK 4
#define DDIM 1024    // model dim
#define BLKN 256     // neurons per block
#define TM 64        // tokens per workgroup tile
#define KS 16        // K-step for LDS staging

static __device__ __forceinline__ float bfbits2f(unsigned short u) {
    unsigned int v = ((unsigned int)u) << 16;
    return __uint_as_float(v);
}

// ---------------- router: logits -> top-4 ids + per-block counts ----------------
__global__ __launch_bounds__(256) void router_kernel(
    const float* __restrict__ x, const float* __restrict__ wr,
    const float* __restrict__ br, int* __restrict__ topk,
    int* __restrict__ counts, int ntok)
{
    int wave = threadIdx.x >> 6;
    int lane = threadIdx.x & 63;
    int t = blockIdx.x * 4 + wave;
    if (t >= ntok) return;

    const float* xt = x + (size_t)t * DDIM;
    float acc[NB];
#pragma unroll
    for (int e = 0; e < NB; ++e) acc[e] = 0.f;

#pragma unroll
    for (int k = 0; k < DDIM / 64; ++k) {
        int d = lane + 64 * k;
        float xv = xt[d];
        const float4* w4 = (const float4*)(wr + (size_t)d * NB);
#pragma unroll
        for (int q = 0; q < 4; ++q) {
            float4 w = w4[q];
            acc[q * 4 + 0] = fmaf(xv, w.x, acc[q * 4 + 0]);
            acc[q * 4 + 1] = fmaf(xv, w.y, acc[q * 4 + 1]);
            acc[q * 4 + 2] = fmaf(xv, w.z, acc[q * 4 + 2]);
            acc[q * 4 + 3] = fmaf(xv, w.w, acc[q * 4 + 3]);
        }
    }
    // butterfly reduce across the 64-lane wave; all lanes end with identical sums
#pragma unroll
    for (int e = 0; e < NB; ++e) {
        float v = acc[e];
#pragma unroll
        for (int off = 32; off > 0; off >>= 1) v += __shfl_xor(v, off, 64);
        acc[e] = v + br[e];
    }
    // softmax is monotonic -> top-k of logits == top-k of probs.
    // tie-break: strict '>' keeps the lower index first (matches lax.top_k).
    unsigned chosen = 0;
    int sel[TOPK];
#pragma unroll
    for (int s = 0; s < TOPK; ++s) {
        float best = -3.0e38f; int bi = 0;
#pragma unroll
        for (int e = 0; e < NB; ++e) {
            bool better = (((chosen >> e) & 1u) == 0u) && (acc[e] > best);
            if (better) { best = acc[e]; bi = e; }
        }
        sel[s] = bi; chosen |= (1u << bi);
    }
    if (lane < TOPK) {
        topk[t * TOPK + lane] = sel[lane];
        atomicAdd(&counts[sel[lane]], 1);
    }
}

// ---------------- exclusive scan of 16 counts ----------------
__global__ void scan_kernel(const int* __restrict__ counts, int* __restrict__ offsets)
{
    if (threadIdx.x == 0) {
        int a = 0;
        for (int e = 0; e < NB; ++e) { offsets[e] = a; a += counts[e]; }
        offsets[NB] = a;
    }
}

// ---------------- build per-block token lists ----------------
__global__ __launch_bounds__(256) void fill_kernel(
    const int* __restrict__ topk, const int* __restrict__ offsets,
    int* __restrict__ cursor, int* __restrict__ tlist, int ntok)
{
    int t = blockIdx.x * 256 + threadIdx.x;
    if (t >= ntok) return;
#pragma unroll
    for (int s = 0; s < TOPK; ++s) {
        int e = topk[t * TOPK + s];
        int pos = atomicAdd(&cursor[e], 1);
        tlist[offsets[e] + pos] = t;
    }
}

// ---------------- out = broadcast(b2) ----------------
__global__ __launch_bounds__(256) void outinit_kernel(
    float* __restrict__ out, const float* __restrict__ b2, int n4)
{
    int i = blockIdx.x * 256 + threadIdx.x;
    if (i < n4) {
        float4 b = ((const float4*)b2)[i & (DDIM / 4 - 1)];
        ((float4*)out)[i] = b;
    }
}

// ---------------- grouped FFN: per (block, token-tile) ----------------
__global__ __launch_bounds__(256) void ffn_kernel(
    const float* __restrict__ x, const float* __restrict__ w1,
    const float* __restrict__ b1, const float* __restrict__ w2,
    const int* __restrict__ offsets, const int* __restrict__ tlist,
    float* __restrict__ out)
{
    __shared__ float Xs[TM][KS + 4];                  // 64x20 f32   (5.0 KB)
    __shared__ float Ws[BLKN][KS + 4];                // 256x20 f32 (20.0 KB) - W1 then W2 tiles
    __shared__ __hip_bfloat16 hS[TM][BLKN + 8];       // 64x264 bf16 (33.0 KB)
    __shared__ int sTok[TM];

    const int e   = blockIdx.x;
    const int mt  = blockIdx.y;
    const int beg = offsets[e];
    const int cnt = offsets[e + 1] - beg;
    if (mt * TM >= cnt) return;                        // uniform early-exit (before any sync)

    const int tid = threadIdx.x;
    const int tm = tid >> 5;    // 0..7 : token group (8 tokens each)
    const int tn = tid & 31;    // 0..31: column group (8 cols, stride 32)

    if (tid < TM) {
        int p = mt * TM + tid;
        sTok[tid] = (p < cnt) ? tlist[beg + p] : -1;
    }
    __syncthreads();

    // ---- phase A: h[64][256] = relu(X_tile @ W1e^T + b1e) ----
    float acc[8][8];
#pragma unroll
    for (int i = 0; i < 8; ++i)
#pragma unroll
        for (int j = 0; j < 8; ++j) acc[i][j] = 0.f;

    const float* w1e = w1 + (size_t)e * BLKN * DDIM;

    for (int k0 = 0; k0 < DDIM; k0 += KS) {
        // stage X tile: 64 tok x 16 k = 256 float4, one per thread
        {
            int row = tid >> 2, c4 = tid & 3;
            int t = sTok[row];
            float4 v = make_float4(0.f, 0.f, 0.f, 0.f);
            if (t >= 0) v = *(const float4*)(x + (size_t)t * DDIM + k0 + c4 * 4);
            *(float4*)(&Xs[row][c4 * 4]) = v;
        }
        // stage W1 tile: 256 n x 16 k = 1024 float4, 4 per thread
#pragma unroll
        for (int r = 0; r < 4; ++r) {
            int v = tid + r * 256;
            int n = v >> 2, c4 = v & 3;
            float4 wv = *(const float4*)(w1e + (size_t)n * DDIM + k0 + c4 * 4);
            *(float4*)(&Ws[n][c4 * 4]) = wv;
        }
        __syncthreads();
#pragma unroll
        for (int kk4 = 0; kk4 < KS / 4; ++kk4) {
            float4 xv[8], wv[8];
#pragma unroll
            for (int i = 0; i < 8; ++i) xv[i] = *(const float4*)(&Xs[tm * 8 + i][kk4 * 4]);
#pragma unroll
            for (int j = 0; j < 8; ++j) wv[j] = *(const float4*)(&Ws[tn + 32 * j][kk4 * 4]);
#pragma unroll
            for (int i = 0; i < 8; ++i)
#pragma unroll
                for (int j = 0; j < 8; ++j) {
                    acc[i][j] = fmaf(xv[i].x, wv[j].x, acc[i][j]);
                    acc[i][j] = fmaf(xv[i].y, wv[j].y, acc[i][j]);
                    acc[i][j] = fmaf(xv[i].z, wv[j].z, acc[i][j]);
                    acc[i][j] = fmaf(xv[i].w, wv[j].w, acc[i][j]);
                }
        }
        __syncthreads();
    }
    // bias + relu -> hS (bf16)
#pragma unroll
    for (int j = 0; j < 8; ++j) {
        int n = tn + 32 * j;
        float b = b1[e * BLKN + n];
#pragma unroll
        for (int i = 0; i < 8; ++i) {
            float hv = acc[i][j] + b;
            hv = hv > 0.f ? hv : 0.f;
            hS[tm * 8 + i][n] = __float2bfloat16(hv);
        }
    }
    __syncthreads();

    // ---- phase B: Y[64][1024] = h @ W2e, in 4 chunks of 256 cols ----
    for (int dc = 0; dc < DDIM; dc += 256) {
        float accB[8][8];
#pragma unroll
        for (int i = 0; i < 8; ++i)
#pragma unroll
            for (int j = 0; j < 8; ++j) accB[i][j] = 0.f;

        for (int b0 = 0; b0 < BLKN; b0 += KS) {
            // stage W2 tile: 256 d-rows x 16 b-cols; element (b,d) = w2[d*4096 + e*256 + b]
#pragma unroll
            for (int r = 0; r < 4; ++r) {
                int v = tid + r * 256;
                int dd2 = v >> 2, c4 = v & 3;
                float4 wv = *(const float4*)(w2 + (size_t)(dc + dd2) * (NB * BLKN) + e * BLKN + b0 + c4 * 4);
                *(float4*)(&Ws[dd2][c4 * 4]) = wv;
            }
            __syncthreads();
#pragma unroll
            for (int kk4 = 0; kk4 < KS / 4; ++kk4) {
                float xh[8][4];
#pragma unroll
                for (int i = 0; i < 8; ++i) {
                    ushort4 hv = *(const ushort4*)(&hS[tm * 8 + i][b0 + kk4 * 4]);
                    xh[i][0] = bfbits2f(hv.x);
                    xh[i][1] = bfbits2f(hv.y);
                    xh[i][2] = bfbits2f(hv.z);
                    xh[i][3] = bfbits2f(hv.w);
                }
                float4 wv[8];
#pragma unroll
                for (int j = 0; j < 8; ++j) wv[j] = *(const float4*)(&Ws[tn + 32 * j][kk4 * 4]);
#pragma unroll
                for (int i = 0; i < 8; ++i)
#pragma unroll
                    for (int j = 0; j < 8; ++j) {
                        accB[i][j] = fmaf(xh[i][0], wv[j].x, accB[i][j]);
                        accB[i][j] = fmaf(xh[i][1], wv[j].y, accB[i][j]);
                        accB[i][j] = fmaf(xh[i][2], wv[j].z, accB[i][j]);
                        accB[i][j] = fmaf(xh[i][3], wv[j].w, accB[i][j]);
                    }
            }
            __syncthreads();
        }
        // scatter-add into out (disjoint token lists per block -> 4 writers/token max)
#pragma unroll
        for (int i = 0; i < 8; ++i) {
            int t = sTok[tm * 8 + i];
            if (t >= 0) {
#pragma unroll
                for (int j = 0; j < 8; ++j) {
                    atomicAdd(out + (size_t)t * DDIM + dc + tn + 32 * j, accB[i][j]);
                }
            }
        }
    }
}

extern "C" void kernel_launch(void* const* d_in, const int* in_sizes, int n_in,
                              void* d_out, int out_size, void* d_ws, size_t ws_size,
                              hipStream_t stream)
{
    (void)n_in; (void)ws_size;
    const float* x  = (const float*)d_in[0];
    const float* wr = (const float*)d_in[1];
    const float* br = (const float*)d_in[2];
    const float* w1 = (const float*)d_in[3];
    const float* b1 = (const float*)d_in[4];
    const float* w2 = (const float*)d_in[5];
    const float* b2 = (const float*)d_in[6];
    float* out = (float*)d_out;
    const int ntok = in_sizes[0] / DDIM;

    int* counts  = (int*)d_ws;              // 16
    int* cursor  = counts + NB;             // 16
    int* offsets = counts + 32;             // 17
    int* topk    = counts + 64;             // ntok*4
    int* tlist   = topk + ntok * TOPK;      // ntok*4

    hipMemsetAsync(d_ws, 0, 32 * sizeof(int), stream);  // zero counts + cursor

    router_kernel<<<dim3((ntok + 3) / 4), dim3(256), 0, stream>>>(x, wr, br, topk, counts, ntok);
    scan_kernel<<<dim3(1), dim3(64), 0, stream>>>(counts, offsets);
    fill_kernel<<<dim3((ntok + 255) / 256), dim3(256), 0, stream>>>(topk, offsets, cursor, tlist, ntok);

    int n4 = ntok * DDIM / 4;
    outinit_kernel<<<dim3((n4 + 255) / 256), dim3(256), 0, stream>>>(out, b2, n4);

    dim3 g(NB, (ntok + TM - 1) / TM);
    ffn_kernel<<<g, dim3(256), 0, stream>>>(x, w1, b1, w2, offsets, tlist, out);
}

// Round 4
// 890.592 us; speedup vs baseline: 2.3796x; 2.3796x over previous
//
#include <hip/hip_runtime.h>
#include <hip/hip_bf16.h>

#define NB 16        // expert blocks
#define TOPK 4
#define DDIM 1024    // model dim
#define BLKN 256     // neurons per block
#define TM 64        // tokens per workgroup tile
#define BK 32        // K-step (== MFMA K)

typedef __attribute__((ext_vector_type(8))) short short8;
typedef __attribute__((ext_vector_type(4))) float f32x4;

// XOR-swizzled byte offset within an LDS tile of row-pitch rowB bytes.
// Bijective per 8-row stripe; write and read must both use it (rule #21).
__device__ __forceinline__ int swz(int row, int kbyte, int rowB) {
    return (row * rowB + kbyte) ^ ((row & 7) << 4);
}

// load 8 contiguous f32 from global, cvt to 8 bf16 (RNE, packed), one ds_write_b128
__device__ __forceinline__ void cvt8_store(const float* __restrict__ g, char* lds, int off) {
    float4 a = *(const float4*)g;
    float4 b = *(const float4*)(g + 4);
    union { __hip_bfloat162 h[4]; short8 s; } u;
    u.h[0] = __float22bfloat162_rn(make_float2(a.x, a.y));
    u.h[1] = __float22bfloat162_rn(make_float2(a.z, a.w));
    u.h[2] = __float22bfloat162_rn(make_float2(b.x, b.y));
    u.h[3] = __float22bfloat162_rn(make_float2(b.z, b.w));
    *(short8*)(lds + off) = u.s;
}

// ---------------- router: logits -> top-4 ids + per-block counts ----------------
__global__ __launch_bounds__(256) void router_kernel(
    const float* __restrict__ x, const float* __restrict__ wr,
    const float* __restrict__ br, int* __restrict__ topk,
    int* __restrict__ counts, int ntok)
{
    int wave = threadIdx.x >> 6;
    int lane = threadIdx.x & 63;
    int t = blockIdx.x * 4 + wave;
    if (t >= ntok) return;

    const float* xt = x + (size_t)t * DDIM;
    float acc[NB];
#pragma unroll
    for (int e = 0; e < NB; ++e) acc[e] = 0.f;

#pragma unroll
    for (int k = 0; k < DDIM / 64; ++k) {
        int d = lane + 64 * k;
        float xv = xt[d];
        const float4* w4 = (const float4*)(wr + (size_t)d * NB);
#pragma unroll
        for (int q = 0; q < 4; ++q) {
            float4 w = w4[q];
            acc[q * 4 + 0] = fmaf(xv, w.x, acc[q * 4 + 0]);
            acc[q * 4 + 1] = fmaf(xv, w.y, acc[q * 4 + 1]);
            acc[q * 4 + 2] = fmaf(xv, w.z, acc[q * 4 + 2]);
            acc[q * 4 + 3] = fmaf(xv, w.w, acc[q * 4 + 3]);
        }
    }
#pragma unroll
    for (int e = 0; e < NB; ++e) {
        float v = acc[e];
#pragma unroll
        for (int off = 32; off > 0; off >>= 1) v += __shfl_xor(v, off, 64);
        acc[e] = v + br[e];
    }
    // softmax monotonic -> top-k of logits; '>' keeps lower index on ties (lax.top_k)
    unsigned chosen = 0;
    int sel[TOPK];
#pragma unroll
    for (int s = 0; s < TOPK; ++s) {
        float best = -3.0e38f; int bi = 0;
#pragma unroll
        for (int e = 0; e < NB; ++e) {
            bool better = (((chosen >> e) & 1u) == 0u) && (acc[e] > best);
            if (better) { best = acc[e]; bi = e; }
        }
        sel[s] = bi; chosen |= (1u << bi);
    }
    if (lane < TOPK) {
        topk[t * TOPK + lane] = sel[lane];
        atomicAdd(&counts[sel[lane]], 1);
    }
}

__global__ void scan_kernel(const int* __restrict__ counts, int* __restrict__ offsets)
{
    if (threadIdx.x == 0) {
        int a = 0;
        for (int e = 0; e < NB; ++e) { offsets[e] = a; a += counts[e]; }
        offsets[NB] = a;
    }
}

__global__ __launch_bounds__(256) void fill_kernel(
    const int* __restrict__ topk, const int* __restrict__ offsets,
    int* __restrict__ cursor, int* __restrict__ tlist, int ntok)
{
    int t = blockIdx.x * 256 + threadIdx.x;
    if (t >= ntok) return;
#pragma unroll
    for (int s = 0; s < TOPK; ++s) {
        int e = topk[t * TOPK + s];
        int pos = atomicAdd(&cursor[e], 1);
        tlist[offsets[e] + pos] = t;
    }
}

__global__ __launch_bounds__(256) void outinit_kernel(
    float* __restrict__ out, const float* __restrict__ b2, int n4)
{
    int i = blockIdx.x * 256 + threadIdx.x;
    if (i < n4) {
        float4 b = ((const float4*)b2)[i & (DDIM / 4 - 1)];
        ((float4*)out)[i] = b;
    }
}

// ---------------- grouped FFN with MFMA: per (block, 64-token tile) ----------------
__global__ __launch_bounds__(256) void ffn_mfma_kernel(
    const float* __restrict__ x, const float* __restrict__ w1,
    const float* __restrict__ b1, const float* __restrict__ w2,
    const int* __restrict__ offsets, const int* __restrict__ tlist,
    float* __restrict__ out)
{
    __shared__ __align__(16) char Xs[TM * BK * 2];       //  4 KB bf16, swizzled
    __shared__ __align__(16) char Ws[BLKN * BK * 2];     // 16 KB bf16, swizzled (W1 and W2 tiles)
    __shared__ __align__(16) char Hs[TM * BLKN * 2];     // 32 KB bf16, swizzled
    __shared__ int sTok[TM];

    const int e   = blockIdx.x;
    const int mt  = blockIdx.y;
    const int beg = offsets[e];
    const int cnt = offsets[e + 1] - beg;
    if (mt * TM >= cnt) return;               // uniform early-exit before any barrier

    const int tid = threadIdx.x;
    const int wv  = tid >> 6;                 // wave 0..3
    const int ln  = tid & 63;
    const int lr  = ln & 15;                  // row/col within fragment
    const int lk  = ln >> 4;                  // k-group 0..3

    if (tid < TM) {
        int p = mt * TM + tid;
        sTok[tid] = (p < cnt) ? tlist[beg + p] : -1;
    }
    __syncthreads();

    // staging geometry: 8 bf16 (16B) per segment
    const int xrow = tid >> 2, xseg = tid & 3;        // X: 64 rows x 4 segs
    const int xtok = sTok[xrow];
    const float* w1e = w1 + (size_t)e * BLKN * DDIM;
    const float* b1e = b1 + e * BLKN;

    // ---- phase A: Hs[tok][n] = relu(X @ W1e^T + b1e), computed as h^T fragments ----
    f32x4 acc[4][4];
#pragma unroll
    for (int i = 0; i < 4; ++i)
#pragma unroll
        for (int j = 0; j < 4; ++j) acc[i][j] = (f32x4)0.f;

    for (int k0 = 0; k0 < DDIM; k0 += BK) {
        __syncthreads();                      // previous iteration's fragment reads done
        {   // stage X tile (zeros for pad rows)
            int off = swz(xrow, xseg * 16, BK * 2);
            if (xtok >= 0) cvt8_store(x + (size_t)xtok * DDIM + k0 + xseg * 8, Xs, off);
            else           *(short8*)(Xs + off) = (short8)0;
        }
#pragma unroll
        for (int r = 0; r < 4; ++r) {         // stage W1 tile: 256 rows x 4 segs
            int v = tid + r * 256;
            int row = v >> 2, seg = v & 3;
            cvt8_store(w1e + (size_t)row * DDIM + k0 + seg * 8, Ws, swz(row, seg * 16, BK * 2));
        }
        __syncthreads();
        short8 af[4], bfr[4];
#pragma unroll
        for (int mi = 0; mi < 4; ++mi)        // A = W1 rows (n-dim is M)
            af[mi] = *(const short8*)(Ws + swz(wv * 64 + mi * 16 + lr, lk * 16, BK * 2));
#pragma unroll
        for (int ni = 0; ni < 4; ++ni)        // B = X^T (tok-dim is N)
            bfr[ni] = *(const short8*)(Xs + swz(ni * 16 + lr, lk * 16, BK * 2));
#pragma unroll
        for (int mi = 0; mi < 4; ++mi)
#pragma unroll
            for (int ni = 0; ni < 4; ++ni)
                acc[mi][ni] = __builtin_amdgcn_mfma_f32_16x16x32_bf16(af[mi], bfr[ni], acc[mi][ni], 0, 0, 0);
    }

    // epilogue A: bias + relu, pack 4 contiguous-n bf16, ds_write_b64 into Hs[tok][n]
#pragma unroll
    for (int mi = 0; mi < 4; ++mi) {
        const int nb = wv * 64 + mi * 16 + lk * 4;        // n-base (4 contiguous)
        const float4 bs = *(const float4*)(b1e + nb);
#pragma unroll
        for (int ni = 0; ni < 4; ++ni) {
            float h0 = fmaxf(acc[mi][ni][0] + bs.x, 0.f);
            float h1 = fmaxf(acc[mi][ni][1] + bs.y, 0.f);
            float h2 = fmaxf(acc[mi][ni][2] + bs.z, 0.f);
            float h3 = fmaxf(acc[mi][ni][3] + bs.w, 0.f);
            union { __hip_bfloat162 h[2]; uint2 u; } pk;
            pk.h[0] = __float22bfloat162_rn(make_float2(h0, h1));
            pk.h[1] = __float22bfloat162_rn(make_float2(h2, h3));
            int row = ni * 16 + lr;                        // token row
            *(uint2*)(Hs + swz(row, nb * 2, BLKN * 2)) = pk.u;
        }
    }

    // token ids for the output scatter (per-lane C rows)
    int tokr[16];
#pragma unroll
    for (int mi = 0; mi < 4; ++mi)
#pragma unroll
        for (int r = 0; r < 4; ++r)
            tokr[mi * 4 + r] = sTok[mi * 16 + lk * 4 + r];

    // ---- phase B: Y[64][1024] = Hs @ W2e, 4 chunks of 256 d-cols ----
    for (int dc = 0; dc < DDIM; dc += 256) {
        f32x4 accB[4][4];
#pragma unroll
        for (int i = 0; i < 4; ++i)
#pragma unroll
            for (int j = 0; j < 4; ++j) accB[i][j] = (f32x4)0.f;

        for (int b0 = 0; b0 < BLKN; b0 += BK) {
            __syncthreads();                  // Hs writes done (1st iter) / prior Ws reads done
#pragma unroll
            for (int r = 0; r < 4; ++r) {     // stage W2 tile: rows = d (256), cols = b (32)
                int v = tid + r * 256;
                int row = v >> 2, seg = v & 3;
                cvt8_store(w2 + (size_t)(dc + row) * (NB * BLKN) + e * BLKN + b0 + seg * 8,
                           Ws, swz(row, seg * 16, BK * 2));
            }
            __syncthreads();
            short8 af[4], bfr[4];
#pragma unroll
            for (int mi = 0; mi < 4; ++mi)    // A = Hs rows (tok)
                af[mi] = *(const short8*)(Hs + swz(mi * 16 + lr, b0 * 2 + lk * 16, BLKN * 2));
#pragma unroll
            for (int ni = 0; ni < 4; ++ni)    // B = W2^T (d-dim is N)
                bfr[ni] = *(const short8*)(Ws + swz(wv * 64 + ni * 16 + lr, lk * 16, BK * 2));
#pragma unroll
            for (int mi = 0; mi < 4; ++mi)
#pragma unroll
                for (int ni = 0; ni < 4; ++ni)
                    accB[mi][ni] = __builtin_amdgcn_mfma_f32_16x16x32_bf16(af[mi], bfr[ni], accB[mi][ni], 0, 0, 0);
        }
        // scatter-add into out (token lists disjoint per expert; <=4 writers/element)
#pragma unroll
        for (int mi = 0; mi < 4; ++mi)
#pragma unroll
            for (int r = 0; r < 4; ++r) {
                int t = tokr[mi * 4 + r];
                if (t >= 0) {
                    float* op = out + (size_t)t * DDIM + dc + wv * 64 + lr;
#pragma unroll
                    for (int ni = 0; ni < 4; ++ni)
                        atomicAdd(op + ni * 16, accB[mi][ni][r]);
                }
            }
    }
}

extern "C" void kernel_launch(void* const* d_in, const int* in_sizes, int n_in,
                              void* d_out, int out_size, void* d_ws, size_t ws_size,
                              hipStream_t stream)
{
    (void)n_in; (void)ws_size; (void)out_size;
    const float* x  = (const float*)d_in[0];
    const float* wr = (const float*)d_in[1];
    const float* br = (const float*)d_in[2];
    const float* w1 = (const float*)d_in[3];
    const float* b1 = (const float*)d_in[4];
    const float* w2 = (const float*)d_in[5];
    const float* b2 = (const float*)d_in[6];
    float* out = (float*)d_out;
    const int ntok = in_sizes[0] / DDIM;

    int* counts  = (int*)d_ws;              // 16
    int* cursor  = counts + NB;             // 16
    int* offsets = counts + 32;             // 17
    int* topk    = counts + 64;             // ntok*4
    int* tlist   = topk + ntok * TOPK;      // ntok*4

    hipMemsetAsync(d_ws, 0, 32 * sizeof(int), stream);

    router_kernel<<<dim3((ntok + 3) / 4), dim3(256), 0, stream>>>(x, wr, br, topk, counts, ntok);
    scan_kernel<<<dim3(1), dim3(64), 0, stream>>>(counts, offsets);
    fill_kernel<<<dim3((ntok + 255) / 256), dim3(256), 0, stream>>>(topk, offsets, cursor, tlist, ntok);

    int n4 = ntok * DDIM / 4;
    outinit_kernel<<<dim3((n4 + 255) / 256), dim3(256), 0, stream>>>(out, b2, n4);

    dim3 g(NB, (ntok + TM - 1) / TM);
    ffn_mfma_kernel<<<g, dim3(256), 0, stream>>>(x, w1, b1, w2, offsets, tlist, out);
}

// Round 5
// 684.083 us; speedup vs baseline: 3.0979x; 1.3019x over previous
//
#include <hip/hip_runtime.h>
#include <hip/hip_bf16.h>

#define NB 16        // expert blocks
#define TOPK 4
#define DDIM 1024    // model dim
#define BLKN 256     // neurons per block
#define TM 64        // tokens per workgroup tile
#define BK 32        // K-step (== MFMA K)

typedef __attribute__((ext_vector_type(8))) short short8;
typedef __attribute__((ext_vector_type(4))) float f32x4;

// ---- ws layout (bytes) ----
#define WRT_OFF (768u * 1024u)                 // transposed router weights, 64 KB
#define WOFF    (1u << 20)                     // bf16 weights base
#define W1BYTES (NB * 32 * 16384)              // 16 experts x 32 k-chunks x 16KB = 8 MB
#define WS_NEEDED ((size_t)WOFF + 2u * (size_t)W1BYTES)   // ~17.8 MB

// byte-level XOR swizzle (used for Hs and by the fallback kernel)
__device__ __forceinline__ int swz(int row, int kbyte, int rowB) {
    return (row * rowB + kbyte) ^ ((row & 7) << 4);
}
// 16B-granule swizzle for 4-granule-per-row tiles (X and W tiles, BK=32 bf16)
__device__ __forceinline__ int gsw(int row, int seg) {
    return (row * 4 + seg) ^ (row & 7);
}

__device__ __forceinline__ short8 pack8(float4 a, float4 b) {
    union { __hip_bfloat162 h[4]; short8 s; } u;
    u.h[0] = __float22bfloat162_rn(make_float2(a.x, a.y));
    u.h[1] = __float22bfloat162_rn(make_float2(a.z, a.w));
    u.h[2] = __float22bfloat162_rn(make_float2(b.x, b.y));
    u.h[3] = __float22bfloat162_rn(make_float2(b.z, b.w));
    return u.s;
}

// direct global->LDS 16B copy; LDS dest = uniform base + lane*16
__device__ __forceinline__ void gll16(const void* g, void* l) {
    __builtin_amdgcn_global_load_lds(
        (const __attribute__((address_space(1))) void*)g,
        (__attribute__((address_space(3))) void*)l, 16, 0, 0);
}

// stage one 16KB pre-swizzled weight chunk: 4 gll calls/thread
__device__ __forceinline__ void stage_w(const char* __restrict__ chunk, char* wbuf,
                                        int wv, int ln) {
#pragma unroll
    for (int c = 0; c < 4; ++c) {
        const int gbase = c * 256 + wv * 64;            // wave-uniform granule base
        gll16(chunk + (size_t)(gbase + ln) * 16, wbuf + gbase * 16);
    }
}

// legacy cvt8 (fallback path)
__device__ __forceinline__ void cvt8_store(const float* __restrict__ g, char* lds, int off) {
    float4 a = *(const float4*)g;
    float4 b = *(const float4*)(g + 4);
    *(short8*)(lds + off) = pack8(a, b);
}

// ---------------- precast: w1 -> bf16, tile-chunked + granule-swizzled ----------------
__global__ __launch_bounds__(256) void precast_w1_kernel(
    const float* __restrict__ w1, char* __restrict__ dst)
{
    int gid = blockIdx.x * 256 + threadIdx.x;      // 524288 granules
    int e   = gid >> 15;                           // 32768 per expert
    int rem = gid & 32767;
    int t   = rem >> 10;                           // k-chunk 0..31
    int g   = rem & 1023;
    int row = g >> 2, seg = g & 3;
    const float* src = w1 + (size_t)(e * BLKN + row) * DDIM + t * BK + seg * 8;
    short8 pk = pack8(*(const float4*)src, *(const float4*)(src + 4));
    *(short8*)(dst + ((size_t)(e * 32 + t) * 1024 + gsw(row, seg)) * 16) = pk;
}

// ---------------- precast: w2 -> bf16 tiles (rows=d_local, cols=b) ----------------
__global__ __launch_bounds__(256) void precast_w2_kernel(
    const float* __restrict__ w2, char* __restrict__ dst)
{
    int gid = blockIdx.x * 256 + threadIdx.x;      // 524288 granules
    int e    = gid >> 15;
    int rem  = gid & 32767;
    int dc   = rem >> 13;                          // d-chunk 0..3
    int rem2 = rem & 8191;
    int st   = rem2 >> 10;                         // b-step 0..7
    int g    = rem2 & 1023;
    int row = g >> 2, seg = g & 3;                 // row = d_local, seg*8 = b offset
    const float* src = w2 + (size_t)(dc * 256 + row) * (NB * BLKN) + e * BLKN + st * BK + seg * 8;
    short8 pk = pack8(*(const float4*)src, *(const float4*)(src + 4));
    *(short8*)(dst + ((size_t)((e * 4 + dc) * 8 + st) * 1024 + gsw(row, seg)) * 16) = pk;
}

// ---------------- transpose router weights: wrt[e][d] = wr[d][e] ----------------
__global__ __launch_bounds__(256) void wrt_kernel(
    const float* __restrict__ wr, float* __restrict__ wrt)
{
    int i = blockIdx.x * 256 + threadIdx.x;        // 16384
    int d = i >> 4, e = i & 15;
    wrt[e * DDIM + d] = wr[i];
}

// ---------------- router (coalesced, transposed weights) ----------------
__global__ __launch_bounds__(256) void router3_kernel(
    const float* __restrict__ x, const float* __restrict__ wrt,
    const float* __restrict__ br, int* __restrict__ topk,
    int* __restrict__ counts, int ntok)
{
    int wave = threadIdx.x >> 6;
    int lane = threadIdx.x & 63;
    int t = blockIdx.x * 4 + wave;
    if (t >= ntok) return;

    const float4* xt4 = (const float4*)(x + (size_t)t * DDIM);
    float acc[NB];
#pragma unroll
    for (int e = 0; e < NB; ++e) acc[e] = 0.f;

#pragma unroll
    for (int k = 0; k < 4; ++k) {
        int d4 = lane + 64 * k;                    // float4 index
        float4 xv = xt4[d4];
#pragma unroll
        for (int e = 0; e < NB; ++e) {
            float4 w = ((const float4*)(wrt + (size_t)e * DDIM))[d4];
            float s = fmaf(xv.x, w.x, fmaf(xv.y, w.y, fmaf(xv.z, w.z, xv.w * w.w)));
            acc[e] += s;
        }
    }
#pragma unroll
    for (int e = 0; e < NB; ++e) {
        float v = acc[e];
#pragma unroll
        for (int off = 32; off > 0; off >>= 1) v += __shfl_xor(v, off, 64);
        acc[e] = v + br[e];
    }
    // softmax monotonic -> top-k of logits; '>' keeps lower index on ties (lax.top_k)
    unsigned chosen = 0;
    int sel[TOPK];
#pragma unroll
    for (int s = 0; s < TOPK; ++s) {
        float best = -3.0e38f; int bi = 0;
#pragma unroll
        for (int e = 0; e < NB; ++e) {
            bool better = (((chosen >> e) & 1u) == 0u) && (acc[e] > best);
            if (better) { best = acc[e]; bi = e; }
        }
        sel[s] = bi; chosen |= (1u << bi);
    }
    if (lane < TOPK) {
        topk[t * TOPK + lane] = sel[lane];
        atomicAdd(&counts[sel[lane]], 1);
    }
}

// legacy router (fallback: reads wr directly, strided)
__global__ __launch_bounds__(256) void router_kernel(
    const float* __restrict__ x, const float* __restrict__ wr,
    const float* __restrict__ br, int* __restrict__ topk,
    int* __restrict__ counts, int ntok)
{
    int wave = threadIdx.x >> 6;
    int lane = threadIdx.x & 63;
    int t = blockIdx.x * 4 + wave;
    if (t >= ntok) return;
    const float* xt = x + (size_t)t * DDIM;
    float acc[NB];
#pragma unroll
    for (int e = 0; e < NB; ++e) acc[e] = 0.f;
#pragma unroll
    for (int k = 0; k < DDIM / 64; ++k) {
        int d = lane + 64 * k;
        float xv = xt[d];
        const float4* w4 = (const float4*)(wr + (size_t)d * NB);
#pragma unroll
        for (int q = 0; q < 4; ++q) {
            float4 w = w4[q];
            acc[q * 4 + 0] = fmaf(xv, w.x, acc[q * 4 + 0]);
            acc[q * 4 + 1] = fmaf(xv, w.y, acc[q * 4 + 1]);
            acc[q * 4 + 2] = fmaf(xv, w.z, acc[q * 4 + 2]);
            acc[q * 4 + 3] = fmaf(xv, w.w, acc[q * 4 + 3]);
        }
    }
#pragma unroll
    for (int e = 0; e < NB; ++e) {
        float v = acc[e];
#pragma unroll
        for (int off = 32; off > 0; off >>= 1) v += __shfl_xor(v, off, 64);
        acc[e] = v + br[e];
    }
    unsigned chosen = 0;
    int sel[TOPK];
#pragma unroll
    for (int s = 0; s < TOPK; ++s) {
        float best = -3.0e38f; int bi = 0;
#pragma unroll
        for (int e = 0; e < NB; ++e) {
            bool better = (((chosen >> e) & 1u) == 0u) && (acc[e] > best);
            if (better) { best = acc[e]; bi = e; }
        }
        sel[s] = bi; chosen |= (1u << bi);
    }
    if (lane < TOPK) {
        topk[t * TOPK + lane] = sel[lane];
        atomicAdd(&counts[sel[lane]], 1);
    }
}

__global__ void scan_kernel(const int* __restrict__ counts, int* __restrict__ offsets)
{
    if (threadIdx.x == 0) {
        int a = 0;
        for (int e = 0; e < NB; ++e) { offsets[e] = a; a += counts[e]; }
        offsets[NB] = a;
    }
}

// ---------------- fill: LDS histogram, 16 global atomics per block ----------------
__global__ __launch_bounds__(256) void fill2_kernel(
    const int* __restrict__ topk, const int* __restrict__ offsets,
    int* __restrict__ cursor, int* __restrict__ tlist, int ntok)
{
    __shared__ int lcnt[NB], lbase[NB];
    int t = blockIdx.x * 256 + threadIdx.x;
    if (threadIdx.x < NB) lcnt[threadIdx.x] = 0;
    __syncthreads();
    int tk[TOPK], lofs[TOPK];
    bool valid = (t < ntok);
    if (valid) {
        int4 v = *(const int4*)(topk + t * TOPK);
        tk[0] = v.x; tk[1] = v.y; tk[2] = v.z; tk[3] = v.w;
#pragma unroll
        for (int s = 0; s < TOPK; ++s) lofs[s] = atomicAdd(&lcnt[tk[s]], 1);
    }
    __syncthreads();
    if (threadIdx.x < NB) lbase[threadIdx.x] = atomicAdd(&cursor[threadIdx.x], lcnt[threadIdx.x]);
    __syncthreads();
    if (valid) {
#pragma unroll
        for (int s = 0; s < TOPK; ++s)
            tlist[offsets[tk[s]] + lbase[tk[s]] + lofs[s]] = t;
    }
}

__global__ __launch_bounds__(256) void outinit_kernel(
    float* __restrict__ out, const float* __restrict__ b2, int n4)
{
    int i = blockIdx.x * 256 + threadIdx.x;
    if (i < n4) {
        float4 b = ((const float4*)b2)[i & (DDIM / 4 - 1)];
        ((float4*)out)[i] = b;
    }
}

// ---------------- FFN v2: bf16 precast weights + global_load_lds + 2-phase pipeline ----------------
__global__ __launch_bounds__(256, 2) void ffn_mfma2_kernel(
    const float* __restrict__ x, const float* __restrict__ b1,
    const int* __restrict__ offsets, const int* __restrict__ tlist,
    const char* __restrict__ wbf, float* __restrict__ out)
{
    __shared__ __align__(16) char Xs[2][TM * BK * 2];     // 2 x 4 KB
    __shared__ __align__(16) char Ws[2][BLKN * BK * 2];   // 2 x 16 KB
    __shared__ __align__(16) char Hs[TM * BLKN * 2];      // 32 KB
    __shared__ int sTok[TM];

    const int e   = blockIdx.x;
    const int mt  = blockIdx.y;
    const int beg = offsets[e];
    const int cnt = offsets[e + 1] - beg;
    if (mt * TM >= cnt) return;               // uniform early-exit before any barrier

    const int tid = threadIdx.x;
    const int wv  = tid >> 6;
    const int ln  = tid & 63;
    const int lr  = ln & 15;
    const int lk  = ln >> 4;

    if (tid < TM) {
        int p = mt * TM + tid;
        sTok[tid] = (p < cnt) ? tlist[beg + p] : -1;
    }
    __syncthreads();

    const int xrow = tid >> 2, xseg = tid & 3;
    const int xtok = sTok[xrow];
    const float* xp = x + (size_t)(xtok < 0 ? 0 : xtok) * DDIM + xseg * 8;
    const char* w1c = wbf + (size_t)e * 32 * 16384;
    const char* w2c = wbf + (size_t)W1BYTES + (size_t)e * 32 * 16384;
    const float* b1e = b1 + e * BLKN;

    // ---- prologue: stage tile 0 ----
    {
        float4 xa = make_float4(0.f, 0.f, 0.f, 0.f), xb = xa;
        if (xtok >= 0) { xa = *(const float4*)xp; xb = *(const float4*)(xp + 4); }
        *(short8*)(Xs[0] + gsw(xrow, xseg) * 16) = pack8(xa, xb);
    }
    stage_w(w1c, Ws[0], wv, ln);
    __syncthreads();

    // ---- phase A: h^T fragments = W1 x X^T ----
    f32x4 acc[4][4];
#pragma unroll
    for (int i = 0; i < 4; ++i)
#pragma unroll
        for (int j = 0; j < 4; ++j) acc[i][j] = (f32x4)0.f;

    for (int t = 0; t < 32; ++t) {
        const int cur = t & 1, nxt = cur ^ 1;
        // prefetch next tile (or first W2 tile on the last iteration)
        float4 xa = make_float4(0.f, 0.f, 0.f, 0.f), xb = xa;
        if (t + 1 < 32) {
            if (xtok >= 0) {
                xa = *(const float4*)(xp + (t + 1) * BK);
                xb = *(const float4*)(xp + (t + 1) * BK + 4);
            }
            stage_w(w1c + (size_t)(t + 1) * 16384, Ws[nxt], wv, ln);
        } else {
            stage_w(w2c, Ws[nxt], wv, ln);
        }
        // compute current
        short8 af[4], bfr[4];
#pragma unroll
        for (int mi = 0; mi < 4; ++mi)
            af[mi] = *(const short8*)(Ws[cur] + gsw(wv * 64 + mi * 16 + lr, lk) * 16);
#pragma unroll
        for (int ni = 0; ni < 4; ++ni)
            bfr[ni] = *(const short8*)(Xs[cur] + gsw(ni * 16 + lr, lk) * 16);
#pragma unroll
        for (int mi = 0; mi < 4; ++mi)
#pragma unroll
            for (int ni = 0; ni < 4; ++ni)
                acc[mi][ni] = __builtin_amdgcn_mfma_f32_16x16x32_bf16(af[mi], bfr[ni], acc[mi][ni], 0, 0, 0);
        // commit next X tile
        if (t + 1 < 32)
            *(short8*)(Xs[nxt] + gsw(xrow, xseg) * 16) = pack8(xa, xb);
        __syncthreads();
    }

    // ---- epilogue A: bias + relu -> Hs[tok][n] (bf16, swizzled rowB=512) ----
#pragma unroll
    for (int mi = 0; mi < 4; ++mi) {
        const int nb = wv * 64 + mi * 16 + lk * 4;
        const float4 bs = *(const float4*)(b1e + nb);
#pragma unroll
        for (int ni = 0; ni < 4; ++ni) {
            float h0 = fmaxf(acc[mi][ni][0] + bs.x, 0.f);
            float h1 = fmaxf(acc[mi][ni][1] + bs.y, 0.f);
            float h2 = fmaxf(acc[mi][ni][2] + bs.z, 0.f);
            float h3 = fmaxf(acc[mi][ni][3] + bs.w, 0.f);
            union { __hip_bfloat162 h[2]; uint2 u; } pk;
            pk.h[0] = __float22bfloat162_rn(make_float2(h0, h1));
            pk.h[1] = __float22bfloat162_rn(make_float2(h2, h3));
            int row = ni * 16 + lr;
            *(uint2*)(Hs + swz(row, nb * 2, BLKN * 2)) = pk.u;
        }
    }

    int tokr[16];
#pragma unroll
    for (int mi = 0; mi < 4; ++mi)
#pragma unroll
        for (int r = 0; r < 4; ++r)
            tokr[mi * 4 + r] = sTok[mi * 16 + lk * 4 + r];
    __syncthreads();

    // ---- phase B: Y = Hs x W2^T, 32 pipelined steps (4 d-chunks x 8 b-steps) ----
    f32x4 accB[4][4];
#pragma unroll
    for (int i = 0; i < 4; ++i)
#pragma unroll
        for (int j = 0; j < 4; ++j) accB[i][j] = (f32x4)0.f;

    for (int s = 0; s < 32; ++s) {
        const int cur = s & 1, nxt = cur ^ 1;
        if (s + 1 < 32)
            stage_w(w2c + (size_t)(s + 1) * 16384, Ws[nxt], wv, ln);
        const int b0 = (s & 7) * BK;
        short8 haf[4], wf[4];
#pragma unroll
        for (int mi = 0; mi < 4; ++mi)
            haf[mi] = *(const short8*)(Hs + swz(mi * 16 + lr, b0 * 2 + lk * 16, BLKN * 2));
#pragma unroll
        for (int ni = 0; ni < 4; ++ni)
            wf[ni] = *(const short8*)(Ws[cur] + gsw(wv * 64 + ni * 16 + lr, lk) * 16);
#pragma unroll
        for (int mi = 0; mi < 4; ++mi)
#pragma unroll
            for (int ni = 0; ni < 4; ++ni)
                accB[mi][ni] = __builtin_amdgcn_mfma_f32_16x16x32_bf16(haf[mi], wf[ni], accB[mi][ni], 0, 0, 0);
        if ((s & 7) == 7) {
            const int dc = (s >> 3) * 256;
#pragma unroll
            for (int mi = 0; mi < 4; ++mi)
#pragma unroll
                for (int r = 0; r < 4; ++r) {
                    int t = tokr[mi * 4 + r];
                    if (t >= 0) {
                        float* op = out + (size_t)t * DDIM + dc + wv * 64 + lr;
#pragma unroll
                        for (int ni = 0; ni < 4; ++ni)
                            atomicAdd(op + ni * 16, accB[mi][ni][r]);
                    }
                }
#pragma unroll
            for (int i = 0; i < 4; ++i)
#pragma unroll
                for (int j = 0; j < 4; ++j) accB[i][j] = (f32x4)0.f;
        }
        __syncthreads();
    }
}

// ---------------- FFN fallback (cvt staging, no pipeline) — known-good ----------------
__global__ __launch_bounds__(256) void ffn_mfma_kernel(
    const float* __restrict__ x, const float* __restrict__ w1,
    const float* __restrict__ b1, const float* __restrict__ w2,
    const int* __restrict__ offsets, const int* __restrict__ tlist,
    float* __restrict__ out)
{
    __shared__ __align__(16) char Xs[TM * BK * 2];
    __shared__ __align__(16) char Ws[BLKN * BK * 2];
    __shared__ __align__(16) char Hs[TM * BLKN * 2];
    __shared__ int sTok[TM];

    const int e   = blockIdx.x;
    const int mt  = blockIdx.y;
    const int beg = offsets[e];
    const int cnt = offsets[e + 1] - beg;
    if (mt * TM >= cnt) return;

    const int tid = threadIdx.x;
    const int wv  = tid >> 6;
    const int ln  = tid & 63;
    const int lr  = ln & 15;
    const int lk  = ln >> 4;

    if (tid < TM) {
        int p = mt * TM + tid;
        sTok[tid] = (p < cnt) ? tlist[beg + p] : -1;
    }
    __syncthreads();

    const int xrow = tid >> 2, xseg = tid & 3;
    const int xtok = sTok[xrow];
    const float* w1e = w1 + (size_t)e * BLKN * DDIM;
    const float* b1e = b1 + e * BLKN;

    f32x4 acc[4][4];
#pragma unroll
    for (int i = 0; i < 4; ++i)
#pragma unroll
        for (int j = 0; j < 4; ++j) acc[i][j] = (f32x4)0.f;

    for (int k0 = 0; k0 < DDIM; k0 += BK) {
        __syncthreads();
        {
            int off = swz(xrow, xseg * 16, BK * 2);
            if (xtok >= 0) cvt8_store(x + (size_t)xtok * DDIM + k0 + xseg * 8, Xs, off);
            else           *(short8*)(Xs + off) = (short8)0;
        }
#pragma unroll
        for (int r = 0; r < 4; ++r) {
            int v = tid + r * 256;
            int row = v >> 2, seg = v & 3;
            cvt8_store(w1e + (size_t)row * DDIM + k0 + seg * 8, Ws, swz(row, seg * 16, BK * 2));
        }
        __syncthreads();
        short8 af[4], bfr[4];
#pragma unroll
        for (int mi = 0; mi < 4; ++mi)
            af[mi] = *(const short8*)(Ws + swz(wv * 64 + mi * 16 + lr, lk * 16, BK * 2));
#pragma unroll
        for (int ni = 0; ni < 4; ++ni)
            bfr[ni] = *(const short8*)(Xs + swz(ni * 16 + lr, lk * 16, BK * 2));
#pragma unroll
        for (int mi = 0; mi < 4; ++mi)
#pragma unroll
            for (int ni = 0; ni < 4; ++ni)
                acc[mi][ni] = __builtin_amdgcn_mfma_f32_16x16x32_bf16(af[mi], bfr[ni], acc[mi][ni], 0, 0, 0);
    }
#pragma unroll
    for (int mi = 0; mi < 4; ++mi) {
        const int nb = wv * 64 + mi * 16 + lk * 4;
        const float4 bs = *(const float4*)(b1e + nb);
#pragma unroll
        for (int ni = 0; ni < 4; ++ni) {
            float h0 = fmaxf(acc[mi][ni][0] + bs.x, 0.f);
            float h1 = fmaxf(acc[mi][ni][1] + bs.y, 0.f);
            float h2 = fmaxf(acc[mi][ni][2] + bs.z, 0.f);
            float h3 = fmaxf(acc[mi][ni][3] + bs.w, 0.f);
            union { __hip_bfloat162 h[2]; uint2 u; } pk;
            pk.h[0] = __float22bfloat162_rn(make_float2(h0, h1));
            pk.h[1] = __float22bfloat162_rn(make_float2(h2, h3));
            int row = ni * 16 + lr;
            *(uint2*)(Hs + swz(row, nb * 2, BLKN * 2)) = pk.u;
        }
    }
    int tokr[16];
#pragma unroll
    for (int mi = 0; mi < 4; ++mi)
#pragma unroll
        for (int r = 0; r < 4; ++r)
            tokr[mi * 4 + r] = sTok[mi * 16 + lk * 4 + r];

    for (int dc = 0; dc < DDIM; dc += 256) {
        f32x4 accB[4][4];
#pragma unroll
        for (int i = 0; i < 4; ++i)
#pragma unroll
            for (int j = 0; j < 4; ++j) accB[i][j] = (f32x4)0.f;

        for (int b0 = 0; b0 < BLKN; b0 += BK) {
            __syncthreads();
#pragma unroll
            for (int r = 0; r < 4; ++r) {
                int v = tid + r * 256;
                int row = v >> 2, seg = v & 3;
                cvt8_store(w2 + (size_t)(dc + row) * (NB * BLKN) + e * BLKN + b0 + seg * 8,
                           Ws, swz(row, seg * 16, BK * 2));
            }
            __syncthreads();
            short8 af[4], bfr[4];
#pragma unroll
            for (int mi = 0; mi < 4; ++mi)
                af[mi] = *(const short8*)(Hs + swz(mi * 16 + lr, b0 * 2 + lk * 16, BLKN * 2));
#pragma unroll
            for (int ni = 0; ni < 4; ++ni)
                bfr[ni] = *(const short8*)(Ws + swz(wv * 64 + ni * 16 + lr, lk * 16, BK * 2));
#pragma unroll
            for (int mi = 0; mi < 4; ++mi)
#pragma unroll
                for (int ni = 0; ni < 4; ++ni)
                    accB[mi][ni] = __builtin_amdgcn_mfma_f32_16x16x32_bf16(af[mi], bfr[ni], accB[mi][ni], 0, 0, 0);
        }
#pragma unroll
        for (int mi = 0; mi < 4; ++mi)
#pragma unroll
            for (int r = 0; r < 4; ++r) {
                int t = tokr[mi * 4 + r];
                if (t >= 0) {
                    float* op = out + (size_t)t * DDIM + dc + wv * 64 + lr;
#pragma unroll
                    for (int ni = 0; ni < 4; ++ni)
                        atomicAdd(op + ni * 16, accB[mi][ni][r]);
                }
            }
    }
}

extern "C" void kernel_launch(void* const* d_in, const int* in_sizes, int n_in,
                              void* d_out, int out_size, void* d_ws, size_t ws_size,
                              hipStream_t stream)
{
    (void)n_in; (void)out_size;
    const float* x  = (const float*)d_in[0];
    const float* wr = (const float*)d_in[1];
    const float* br = (const float*)d_in[2];
    const float* w1 = (const float*)d_in[3];
    const float* b1 = (const float*)d_in[4];
    const float* w2 = (const float*)d_in[5];
    const float* b2 = (const float*)d_in[6];
    float* out = (float*)d_out;
    const int ntok = in_sizes[0] / DDIM;

    int* counts  = (int*)d_ws;
    int* cursor  = counts + NB;
    int* offsets = counts + 32;
    int* topk    = counts + 64;
    int* tlist   = topk + ntok * TOPK;

    const bool big = (ws_size >= WS_NEEDED);
    float* wrt = (float*)((char*)d_ws + WRT_OFF);
    char*  wbf = (char*)d_ws + WOFF;

    hipMemsetAsync(d_ws, 0, 32 * sizeof(int), stream);

    if (big) {
        wrt_kernel<<<dim3(64), dim3(256), 0, stream>>>(wr, wrt);
        precast_w1_kernel<<<dim3(2048), dim3(256), 0, stream>>>(w1, wbf);
        precast_w2_kernel<<<dim3(2048), dim3(256), 0, stream>>>(w2, wbf + W1BYTES);
        router3_kernel<<<dim3((ntok + 3) / 4), dim3(256), 0, stream>>>(x, wrt, br, topk, counts, ntok);
    } else {
        router_kernel<<<dim3((ntok + 3) / 4), dim3(256), 0, stream>>>(x, wr, br, topk, counts, ntok);
    }
    scan_kernel<<<dim3(1), dim3(64), 0, stream>>>(counts, offsets);
    fill2_kernel<<<dim3((ntok + 255) / 256), dim3(256), 0, stream>>>(topk, offsets, cursor, tlist, ntok);

    int n4 = ntok * DDIM / 4;
    outinit_kernel<<<dim3((n4 + 255) / 256), dim3(256), 0, stream>>>(out, b2, n4);

    dim3 g(NB, (ntok + TM - 1) / TM);
    if (big) {
        ffn_mfma2_kernel<<<g, dim3(256), 0, stream>>>(x, b1, offsets, tlist, wbf, out);
    } else {
        ffn_mfma_kernel<<<g, dim3(256), 0, stream>>>(x, w1, b1, w2, offsets, tlist, out);
    }
}

// Round 9
// 560.769 us; speedup vs baseline: 3.7791x; 1.2199x over previous
//
#include <hip/hip_runtime.h>
#include <hip/hip_bf16.h>

#define NB 16        // expert blocks
#define TOPK 4
#define DDIM 1024    // model dim
#define BLKN 256     // neurons per block
#define TM 64        // tokens per workgroup tile
#define BK 32        // K-step (== MFMA K)

typedef __attribute__((ext_vector_type(8))) short short8;
typedef __attribute__((ext_vector_type(4))) float f32x4;

// ---- ws layout (bytes) ----
// [0,128): counts(16), cursor(16)
// [1KB..): topk (ntok*4 int), slots (ntok*4 int), tlist (ntok*4 int)
#define WOFF     (1u << 20)                    // bf16 weights base (1 MB)
#define W1BYTES  (NB * 32 * 16384)             // 8 MB
#define SLAB_OFF ((size_t)WOFF + 2u * (size_t)W1BYTES)   // 17 MB
// slab bytes = ntok*TOPK*DDIM*2 (bf16) — checked at launch

// byte-level XOR swizzle (Hs tile)
__device__ __forceinline__ int swz(int row, int kbyte, int rowB) {
    return (row * rowB + kbyte) ^ ((row & 7) << 4);
}
// 16B-granule swizzle for 4-granule-per-row tiles (X and W tiles, BK=32 bf16)
__device__ __forceinline__ int gsw(int row, int seg) {
    return (row * 4 + seg) ^ (row & 7);
}

__device__ __forceinline__ short8 pack8(float4 a, float4 b) {
    union { __hip_bfloat162 h[4]; short8 s; } u;
    u.h[0] = __float22bfloat162_rn(make_float2(a.x, a.y));
    u.h[1] = __float22bfloat162_rn(make_float2(a.z, a.w));
    u.h[2] = __float22bfloat162_rn(make_float2(b.x, b.y));
    u.h[3] = __float22bfloat162_rn(make_float2(b.z, b.w));
    return u.s;
}

__device__ __forceinline__ float bfu2f(unsigned short u) {
    return __uint_as_float(((unsigned int)u) << 16);
}

// direct global->LDS 16B copy; LDS dest = uniform base + lane*16
__device__ __forceinline__ void gll16(const void* g, void* l) {
    __builtin_amdgcn_global_load_lds(
        (const __attribute__((address_space(1))) void*)g,
        (__attribute__((address_space(3))) void*)l, 16, 0, 0);
}

// stage one 16KB pre-swizzled weight chunk: 4 gll calls/thread
__device__ __forceinline__ void stage_w(const char* __restrict__ chunk, char* wbuf,
                                        int wv, int ln) {
#pragma unroll
    for (int c = 0; c < 4; ++c) {
        const int gbase = c * 256 + wv * 64;
        gll16(chunk + (size_t)(gbase + ln) * 16, wbuf + gbase * 16);
    }
}

// ---------------- prep: w1 + w2 -> bf16, tile-chunked + granule-swizzled ----------------
__global__ __launch_bounds__(256) void prep_kernel(
    const float* __restrict__ w1, const float* __restrict__ w2, char* __restrict__ wbf)
{
    int bid = blockIdx.x;
    if (bid < 2048) {                 // --- w1: [e][n][k] -> chunks [e*32+t] of [256 rows][4 segs]
        int gid = bid * 256 + threadIdx.x;
        int e   = gid >> 15;
        int rem = gid & 32767;
        int t   = rem >> 10;
        int g   = rem & 1023;
        int row = g >> 2, seg = g & 3;
        const float* src = w1 + (size_t)(e * BLKN + row) * DDIM + t * BK + seg * 8;
        short8 pk = pack8(*(const float4*)src, *(const float4*)(src + 4));
        *(short8*)(wbf + ((size_t)(e * 32 + t) * 1024 + gsw(row, seg)) * 16) = pk;
    } else {                          // --- w2: rows=d_local, cols=b
        int gid = (bid - 2048) * 256 + threadIdx.x;
        int e    = gid >> 15;
        int rem  = gid & 32767;
        int dc   = rem >> 13;
        int rem2 = rem & 8191;
        int st   = rem2 >> 10;
        int g    = rem2 & 1023;
        int row = g >> 2, seg = g & 3;
        const float* src = w2 + (size_t)(dc * 256 + row) * (NB * BLKN) + e * BLKN + st * BK + seg * 8;
        short8 pk = pack8(*(const float4*)src, *(const float4*)(src + 4));
        *(short8*)(wbf + (size_t)W1BYTES + ((size_t)((e * 4 + dc) * 8 + st) * 1024 + gsw(row, seg)) * 16) = pk;
    }
}

// ---------------- router: 16 tokens/block, router weights staged in LDS ----------------
// LDS layout: 16 experts x 256 granules(16B), granule g stored at g^(e&7) within row.
__global__ __launch_bounds__(1024) void router4_kernel(
    const float* __restrict__ x, const float* __restrict__ wr,
    const float* __restrict__ br, int* __restrict__ topk,
    int* __restrict__ counts, int ntok)
{
    __shared__ __align__(16) float wrL[NB * 1024];     // 64 KB
    const int tid = threadIdx.x;

    // load wr [1024][16] coalesced as float4 (4 consecutive e, same d), scatter-transpose
#pragma unroll
    for (int it = 0; it < 4; ++it) {
        int i4 = it * 1024 + tid;                       // float4 index into wr
        float4 v = ((const float4*)wr)[i4];
        int d = (i4 * 4) >> 4, e0 = (i4 * 4) & 15;      // e0 in {0,4,8,12}
        int g = d >> 2, c = d & 3;                      // granule, float-within-granule
#pragma unroll
        for (int q = 0; q < 4; ++q) {
            int e = e0 + q;
            float vv = (q == 0) ? v.x : (q == 1) ? v.y : (q == 2) ? v.z : v.w;
            wrL[e * 1024 + (g ^ (e & 7)) * 4 + c] = vv;
        }
    }
    __syncthreads();

    const int wave = tid >> 6, lane = tid & 63;
    const int t = blockIdx.x * 16 + wave;
    if (t < ntok) {
        const float4* xt4 = (const float4*)(x + (size_t)t * DDIM);
        float acc[NB];
#pragma unroll
        for (int e = 0; e < NB; ++e) acc[e] = 0.f;
#pragma unroll
        for (int k = 0; k < 4; ++k) {
            int g = lane + 64 * k;                      // granule index = float4 index
            float4 xv = xt4[g];
#pragma unroll
            for (int e = 0; e < NB; ++e) {
                float4 w = *(const float4*)(&wrL[e * 1024 + (g ^ (e & 7)) * 4]);
                acc[e] += fmaf(xv.x, w.x, fmaf(xv.y, w.y, fmaf(xv.z, w.z, xv.w * w.w)));
            }
        }
#pragma unroll
        for (int e = 0; e < NB; ++e) {
            float v = acc[e];
#pragma unroll
            for (int off = 32; off > 0; off >>= 1) v += __shfl_xor(v, off, 64);
            acc[e] = v + br[e];
        }
        // softmax monotonic -> top-k of logits; '>' keeps lower index on ties (lax.top_k)
        unsigned chosen = 0;
        int sel[TOPK];
#pragma unroll
        for (int s = 0; s < TOPK; ++s) {
            float best = -3.0e38f; int bi = 0;
#pragma unroll
            for (int e = 0; e < NB; ++e) {
                bool better = (((chosen >> e) & 1u) == 0u) && (acc[e] > best);
                if (better) { best = acc[e]; bi = e; }
            }
            sel[s] = bi; chosen |= (1u << bi);
        }
        if (lane < TOPK) {
            topk[t * TOPK + lane] = sel[lane];
            atomicAdd(&counts[sel[lane]], 1);
        }
    }
}

// ---------------- fill: local scan of counts + LDS histogram; records slot per (t,s) ----------------
__global__ __launch_bounds__(256) void fill3_kernel(
    const int* __restrict__ topk, const int* __restrict__ counts,
    int* __restrict__ cursor, int* __restrict__ tlist, int* __restrict__ slots, int ntok)
{
    __shared__ int lcnt[NB], lbase[NB], loff[NB];
    int t = blockIdx.x * 256 + threadIdx.x;
    if (threadIdx.x < NB) lcnt[threadIdx.x] = 0;
    if (threadIdx.x == 0) {
        int a = 0;
#pragma unroll
        for (int e = 0; e < NB; ++e) { loff[e] = a; a += counts[e]; }
    }
    __syncthreads();
    int tk[TOPK], lofs[TOPK];
    bool valid = (t < ntok);
    if (valid) {
        int4 v = *(const int4*)(topk + t * TOPK);
        tk[0] = v.x; tk[1] = v.y; tk[2] = v.z; tk[3] = v.w;
#pragma unroll
        for (int s = 0; s < TOPK; ++s) lofs[s] = atomicAdd(&lcnt[tk[s]], 1);
    }
    __syncthreads();
    if (threadIdx.x < NB) lbase[threadIdx.x] = atomicAdd(&cursor[threadIdx.x], lcnt[threadIdx.x]);
    __syncthreads();
    if (valid) {
#pragma unroll
        for (int s = 0; s < TOPK; ++s) {
            int slot = loff[tk[s]] + lbase[tk[s]] + lofs[s];
            tlist[slot] = t;
            slots[t * TOPK + s] = slot;
        }
    }
}

__global__ __launch_bounds__(256) void outinit_kernel(
    float* __restrict__ out, const float* __restrict__ b2, int n4)
{
    int i = blockIdx.x * 256 + threadIdx.x;
    if (i < n4) {
        float4 b = ((const float4*)b2)[i & (DDIM / 4 - 1)];
        ((float4*)out)[i] = b;
    }
}

// ---------------- reduce: out[t] = b2 + sum_s slab[slots[t][s]] ----------------
__global__ __launch_bounds__(256) void reduce_kernel(
    const unsigned short* __restrict__ slab, const int* __restrict__ slots,
    const float* __restrict__ b2, float* __restrict__ out, int ntok)
{
    int t = blockIdx.x * 4 + (threadIdx.x >> 6);
    int ln = threadIdx.x & 63;
    if (t >= ntok) return;
    int4 s4 = *(const int4*)(slots + t * TOPK);
    const unsigned short* r0 = slab + (size_t)s4.x * DDIM;
    const unsigned short* r1 = slab + (size_t)s4.y * DDIM;
    const unsigned short* r2 = slab + (size_t)s4.z * DDIM;
    const unsigned short* r3 = slab + (size_t)s4.w * DDIM;
    float* op = out + (size_t)t * DDIM;
#pragma unroll
    for (int it = 0; it < 4; ++it) {
        int c = it * 256 + ln * 4;
        float4 v = *(const float4*)(b2 + c);
#pragma unroll
        for (int s = 0; s < 4; ++s) {
            const unsigned short* rp = (s == 0) ? r0 : (s == 1) ? r1 : (s == 2) ? r2 : r3;
            ushort4 u = *(const ushort4*)(rp + c);
            v.x += bfu2f(u.x); v.y += bfu2f(u.y); v.z += bfu2f(u.z); v.w += bfu2f(u.w);
        }
        *(float4*)(op + c) = v;
    }
}

// ---------------- FFN: bf16 weights + gll staging + 2-phase pipeline ----------------
// grid = (tiles fastest, experts slowest) for per-XCD L2 weight locality.
// slab_mode: fc2 writes bf16 partials to slab rows (collision-free); else atomics to out.
__global__ __launch_bounds__(256, 2) void ffn3_kernel(
    const float* __restrict__ x, const float* __restrict__ b1,
    const int* __restrict__ counts, const int* __restrict__ tlist,
    const char* __restrict__ wbf, unsigned short* __restrict__ slab,
    float* __restrict__ out, int slab_mode)
{
    __shared__ __align__(16) char Xs[2][TM * BK * 2];     // 2 x 4 KB
    __shared__ __align__(16) char Ws[2][BLKN * BK * 2];   // 2 x 16 KB
    __shared__ __align__(16) char Hs[TM * BLKN * 2];      // 32 KB
    __shared__ int sTok[TM];

    const int mt = blockIdx.x;
    const int e  = blockIdx.y;
    int beg = 0;
#pragma unroll
    for (int i = 0; i < NB; ++i) beg += (i < e) ? counts[i] : 0;
    const int cnt = counts[e];
    if (mt * TM >= cnt) return;               // uniform early-exit before any barrier

    const int tid = threadIdx.x;
    const int wv  = tid >> 6;
    const int ln  = tid & 63;
    const int lr  = ln & 15;
    const int lk  = ln >> 4;

    if (tid < TM) {
        int p = mt * TM + tid;
        sTok[tid] = (p < cnt) ? tlist[beg + p] : -1;
    }
    __syncthreads();

    const int xrow = tid >> 2, xseg = tid & 3;
    const int xtok = sTok[xrow];
    const float* xp = x + (size_t)(xtok < 0 ? 0 : xtok) * DDIM + xseg * 8;
    const char* w1c = wbf + (size_t)e * 32 * 16384;
    const char* w2c = wbf + (size_t)W1BYTES + (size_t)e * 32 * 16384;
    const float* b1e = b1 + e * BLKN;

    // ---- prologue: stage tile 0 ----
    {
        float4 xa = make_float4(0.f, 0.f, 0.f, 0.f), xb = xa;
        if (xtok >= 0) { xa = *(const float4*)xp; xb = *(const float4*)(xp + 4); }
        *(short8*)(Xs[0] + gsw(xrow, xseg) * 16) = pack8(xa, xb);
    }
    stage_w(w1c, Ws[0], wv, ln);
    __syncthreads();

    // ---- phase A: h^T fragments = W1 x X^T ----
    f32x4 acc[4][4];
#pragma unroll
    for (int i = 0; i < 4; ++i)
#pragma unroll
        for (int j = 0; j < 4; ++j) acc[i][j] = (f32x4)0.f;

    for (int t = 0; t < 32; ++t) {
        const int cur = t & 1, nxt = cur ^ 1;
        float4 xa = make_float4(0.f, 0.f, 0.f, 0.f), xb = xa;
        if (t + 1 < 32) {
            if (xtok >= 0) {
                xa = *(const float4*)(xp + (t + 1) * BK);
                xb = *(const float4*)(xp + (t + 1) * BK + 4);
            }
            stage_w(w1c + (size_t)(t + 1) * 16384, Ws[nxt], wv, ln);
        } else {
            stage_w(w2c, Ws[nxt], wv, ln);
        }
        short8 af[4], bfr[4];
#pragma unroll
        for (int mi = 0; mi < 4; ++mi)
            af[mi] = *(const short8*)(Ws[cur] + gsw(wv * 64 + mi * 16 + lr, lk) * 16);
#pragma unroll
        for (int ni = 0; ni < 4; ++ni)
            bfr[ni] = *(const short8*)(Xs[cur] + gsw(ni * 16 + lr, lk) * 16);
#pragma unroll
        for (int mi = 0; mi < 4; ++mi)
#pragma unroll
            for (int ni = 0; ni < 4; ++ni)
                acc[mi][ni] = __builtin_amdgcn_mfma_f32_16x16x32_bf16(af[mi], bfr[ni], acc[mi][ni], 0, 0, 0);
        if (t + 1 < 32)
            *(short8*)(Xs[nxt] + gsw(xrow, xseg) * 16) = pack8(xa, xb);
        __syncthreads();
    }

    // ---- epilogue A: bias + relu -> Hs[tok][n] ----
#pragma unroll
    for (int mi = 0; mi < 4; ++mi) {
        const int nb = wv * 64 + mi * 16 + lk * 4;
        const float4 bs = *(const float4*)(b1e + nb);
#pragma unroll
        for (int ni = 0; ni < 4; ++ni) {
            float h0 = fmaxf(acc[mi][ni][0] + bs.x, 0.f);
            float h1 = fmaxf(acc[mi][ni][1] + bs.y, 0.f);
            float h2 = fmaxf(acc[mi][ni][2] + bs.z, 0.f);
            float h3 = fmaxf(acc[mi][ni][3] + bs.w, 0.f);
            union { __hip_bfloat162 h[2]; uint2 u; } pk;
            pk.h[0] = __float22bfloat162_rn(make_float2(h0, h1));
            pk.h[1] = __float22bfloat162_rn(make_float2(h2, h3));
            int row = ni * 16 + lr;
            *(uint2*)(Hs + swz(row, nb * 2, BLKN * 2)) = pk.u;
        }
    }

    // per-lane token ids for fc2's C columns: token_local = ni*16 + lr
    int stok4[4];
#pragma unroll
    for (int ni = 0; ni < 4; ++ni) stok4[ni] = sTok[ni * 16 + lr];
    __syncthreads();

    // ---- phase B (swapped): C[d][tok] = W2 x H^T; lane holds 4 CONTIGUOUS d per frag ----
    f32x4 accB[4][4];
#pragma unroll
    for (int i = 0; i < 4; ++i)
#pragma unroll
        for (int j = 0; j < 4; ++j) accB[i][j] = (f32x4)0.f;

    for (int s = 0; s < 32; ++s) {
        const int cur = s & 1, nxt = cur ^ 1;
        if (s + 1 < 32)
            stage_w(w2c + (size_t)(s + 1) * 16384, Ws[nxt], wv, ln);
        const int b0 = (s & 7) * BK;
        short8 haf[4], wf[4];
#pragma unroll
        for (int ni = 0; ni < 4; ++ni)     // B = H rows (tok), k = n
            haf[ni] = *(const short8*)(Hs + swz(ni * 16 + lr, b0 * 2 + lk * 16, BLKN * 2));
#pragma unroll
        for (int mi = 0; mi < 4; ++mi)     // A = W2 rows (d), k = n
            wf[mi] = *(const short8*)(Ws[cur] + gsw(wv * 64 + mi * 16 + lr, lk) * 16);
#pragma unroll
        for (int mi = 0; mi < 4; ++mi)
#pragma unroll
            for (int ni = 0; ni < 4; ++ni)
                accB[mi][ni] = __builtin_amdgcn_mfma_f32_16x16x32_bf16(wf[mi], haf[ni], accB[mi][ni], 0, 0, 0);
        if ((s & 7) == 7) {
            const int dc = (s >> 3) * 256;
            const int d0 = dc + wv * 64 + lk * 4;        // 4 contiguous d per (mi) frag
            if (slab_mode) {
#pragma unroll
                for (int ni = 0; ni < 4; ++ni) {
                    if (stok4[ni] >= 0) {
                        unsigned short* rp = slab + (size_t)(beg + mt * TM + ni * 16 + lr) * DDIM + d0;
#pragma unroll
                        for (int mi = 0; mi < 4; ++mi) {
                            union { __hip_bfloat162 h[2]; uint2 u; } pk;
                            pk.h[0] = __float22bfloat162_rn(make_float2(accB[mi][ni][0], accB[mi][ni][1]));
                            pk.h[1] = __float22bfloat162_rn(make_float2(accB[mi][ni][2], accB[mi][ni][3]));
                            *(uint2*)(rp + mi * 16) = pk.u;
                        }
                    }
                }
            } else {
#pragma unroll
                for (int ni = 0; ni < 4; ++ni) {
                    int t2 = stok4[ni];
                    if (t2 >= 0) {
                        float* op = out + (size_t)t2 * DDIM + d0;
#pragma unroll
                        for (int mi = 0; mi < 4; ++mi)
#pragma unroll
                            for (int r = 0; r < 4; ++r)
                                atomicAdd(op + mi * 16 + r, accB[mi][ni][r]);
                    }
                }
            }
#pragma unroll
            for (int i = 0; i < 4; ++i)
#pragma unroll
                for (int j = 0; j < 4; ++j) accB[i][j] = (f32x4)0.f;
        }
        __syncthreads();
    }
}

extern "C" void kernel_launch(void* const* d_in, const int* in_sizes, int n_in,
                              void* d_out, int out_size, void* d_ws, size_t ws_size,
                              hipStream_t stream)
{
    (void)n_in; (void)out_size;
    const float* x  = (const float*)d_in[0];
    const float* wr = (const float*)d_in[1];
    const float* br = (const float*)d_in[2];
    const float* w1 = (const float*)d_in[3];
    const float* b1 = (const float*)d_in[4];
    const float* w2 = (const float*)d_in[5];
    const float* b2 = (const float*)d_in[6];
    float* out = (float*)d_out;
    const int ntok = in_sizes[0] / DDIM;

    int* counts  = (int*)d_ws;                     // 16
    int* cursor  = counts + NB;                    // 16
    int* topk    = (int*)((char*)d_ws + 1024);     // ntok*4
    int* slots   = topk + ntok * TOPK;             // ntok*4
    int* tlist   = slots + ntok * TOPK;            // ntok*4
    char* wbf    = (char*)d_ws + WOFF;
    unsigned short* slab = (unsigned short*)((char*)d_ws + SLAB_OFF);

    const size_t slab_bytes = (size_t)ntok * TOPK * DDIM * 2;
    const int slab_mode = (ws_size >= SLAB_OFF + slab_bytes) ? 1 : 0;

    hipMemsetAsync(d_ws, 0, 32 * sizeof(int), stream);

    prep_kernel<<<dim3(4096), dim3(256), 0, stream>>>(w1, w2, wbf);
    router4_kernel<<<dim3((ntok + 15) / 16), dim3(1024), 0, stream>>>(x, wr, br, topk, counts, ntok);
    fill3_kernel<<<dim3((ntok + 255) / 256), dim3(256), 0, stream>>>(topk, counts, cursor, tlist, slots, ntok);

    if (!slab_mode) {
        int n4 = ntok * DDIM / 4;
        outinit_kernel<<<dim3((n4 + 255) / 256), dim3(256), 0, stream>>>(out, b2, n4);
    }

    dim3 g((ntok + TM - 1) / TM, NB);              // tiles fastest, experts slowest (L2 locality)
    ffn3_kernel<<<g, dim3(256), 0, stream>>>(x, b1, counts, tlist, wbf, slab, out, slab_mode);

    if (slab_mode) {
        reduce_kernel<<<dim3((ntok + 3) / 4), dim3(256), 0, stream>>>(slab, slots, b2, out, ntok);
    }
}